// Round 1
// baseline (214.894 us; speedup 1.0000x reference)
//
#include <hip/hip_runtime.h>
#include <hip/hip_bf16.h>

#define NGRAPH 16
#define NNODE 1024
#define DDIM 64

typedef __attribute__((ext_vector_type(8))) short bf16x8;
typedef __attribute__((ext_vector_type(4))) float f32x4;

// ---- workspace layout (float offsets) ----
#define OFF_ROWSUM 0            // 16384
#define OFF_DIAG   16384        // 16384
#define OFF_P1     32768        // 16384
#define OFF_R      49152        // 16384
#define OFF_CS     65536        // 16*8*64 = 8192
#define OFF_S      73728        // 16 (+ pad)
#define OFF_S2P    75840        // 16384
#define OFF_R2P    92224        // 16384
#define OFF_BASE0  110656       // 16*1024*64 = 1048576
#define OFF_X2T    1159232      // ushort area: 16*64*1024 ushorts = 524288 floats

__device__ __forceinline__ unsigned short f2bf(float f) {
    unsigned int u = __float_as_uint(f);
    u = (u + 0x7fffu + ((u >> 16) & 1u)) >> 16;
    return (unsigned short)u;
}

// single-instruction packed f32->bf16 (RNE, same rounding as f2bf)
__device__ __forceinline__ unsigned int cvt_pk_bf16(float lo, float hi) {
    unsigned int r;
    asm("v_cvt_pk_bf16_f32 %0, %1, %2" : "=v"(r) : "v"(lo), "v"(hi));
    return r;
}

__device__ __forceinline__ float wave_reduce(float v) {
    #pragma unroll
    for (int off = 32; off; off >>= 1) v += __shfl_down(v, off, 64);
    return v;
}

// ---------------- kA: A row sums + diag  |  X column sums + p1 = X @ wA1 ----------------
__global__ __launch_bounds__(256) void kA_stats(const float* __restrict__ A,
                                                const float* __restrict__ X,
                                                const float* __restrict__ wA1,
                                                float* __restrict__ rowsum,
                                                float* __restrict__ diagv,
                                                float* __restrict__ p1,
                                                float* __restrict__ colsum_part) {
    if (blockIdx.x < NGRAPH * NNODE / 4) {
        int row  = blockIdx.x * 4 + (threadIdx.x >> 6);
        int lane = threadIdx.x & 63;
        const float4* b4 = (const float4*)(A + (size_t)row * NNODE);
        float sum = 0.f;
        #pragma unroll
        for (int it = 0; it < 4; ++it) {
            float4 v = b4[lane + it * 64];
            sum += v.x + v.y + v.z + v.w;
        }
        sum = wave_reduce(sum);
        if (lane == 0) {
            rowsum[row] = sum;
            int i = row & (NNODE - 1);
            diagv[row] = ((const float*)b4)[i];
        }
    } else {
        int bid  = blockIdx.x - NGRAPH * NNODE / 4;
        int b    = bid >> 3;
        int blk  = bid & 7;
        int wv   = threadIdx.x >> 6;
        int lane = threadIdx.x & 63;
        float w = wA1[lane];
        float cs = 0.f;
        int row0 = blk * 128 + wv * 32;
        const float* Xb = X + (size_t)b * NNODE * DDIM;
        for (int rI = 0; rI < 32; ++rI) {
            int i = row0 + rI;
            float x = Xb[i * DDIM + lane];
            cs += x;
            float v = wave_reduce(x * w);
            if (lane == 0) p1[b * NNODE + i] = v;
        }
        __shared__ float csl[4][64];
        csl[wv][lane] = cs;
        __syncthreads();
        if (threadIdx.x < 64) {
            float t = csl[0][lane] + csl[1][lane] + csl[2][lane] + csl[3][lane];
            colsum_part[(b * 8 + blk) * 64 + lane] = t;
        }
    }
}

// ---------------- kB: per-graph stats (recomputed per block) + per-node transforms ----------------
__global__ __launch_bounds__(256) void kB_nodes(const float* __restrict__ X,
                                                const float* __restrict__ coeffs,
                                                const float* __restrict__ wA2,
                                                const float* __restrict__ w11,
                                                const float* __restrict__ w12,
                                                const float* __restrict__ w13,
                                                const float* __restrict__ w14,
                                                const float* __restrict__ w15,
                                                const float* __restrict__ w16,
                                                const float* __restrict__ w21,
                                                const float* __restrict__ w22,
                                                const float* __restrict__ w23,
                                                const float* __restrict__ w24,
                                                const float* __restrict__ w25,
                                                const float* __restrict__ w26,
                                                const float* __restrict__ rowsum,
                                                const float* __restrict__ diagv,
                                                const float* __restrict__ colsum_part,
                                                const float* __restrict__ p1g,
                                                float* __restrict__ rws,
                                                float* __restrict__ base0,
                                                unsigned short* __restrict__ x2tg,
                                                float* __restrict__ S2part,
                                                float* __restrict__ R2part,
                                                float* __restrict__ sArr) {
    __shared__ float Xl[64][68];
    __shared__ float w1l[64][68];
    __shared__ float w2l[64][68];
    __shared__ unsigned short X2Tl[64][68];
    __shared__ float rm_l[64], dg_l[64], r_l[64];
    __shared__ float redS[4][64], redR[4][64];
    __shared__ float redA[4], redD[4];
    __shared__ float mxs[64], p2s;
    __shared__ float pg1_l[64], pg2_l[64];

    int b    = blockIdx.x >> 4;
    int tile = blockIdx.x & 15;
    int i0   = tile * 64;
    int tid  = threadIdx.x;
    int e    = tid & 63;
    int wv   = tid >> 6;

    // --- stage X tile + weights ---
    const float* Xg = X + (size_t)b * (NNODE * DDIM) + (size_t)i0 * DDIM;
    #pragma unroll
    for (int it = 0; it < 4; ++it) {
        int g   = it * 256 + tid;
        int row = g >> 4;
        int c4  = (g & 15) << 2;
        float4 v  = ((const float4*)Xg)[g];
        *(float4*)&Xl[row][c4] = v;
        float4 v1 = ((const float4*)w11)[g];
        *(float4*)&w1l[row][c4] = v1;
        float4 v2 = ((const float4*)w21)[g];
        *(float4*)&w2l[row][c4] = v2;
    }

    // --- per-graph scalar stats (every block recomputes; cheap) ---
    float sa = 0.f, sd = 0.f;
    for (int i = tid; i < NNODE; i += 256) {
        sa += rowsum[b * NNODE + i];
        sd += diagv[b * NNODE + i];
    }
    sa = wave_reduce(sa); sd = wave_reduce(sd);
    if (e == 0) { redA[wv] = sa; redD[wv] = sd; }
    if (tid < 64) {
        float mx = 0.f;
        for (int k = 0; k < 8; ++k) mx += colsum_part[(b * 8 + k) * 64 + tid];
        mxs[tid] = mx * (1.f / (float)NNODE);
    }
    __syncthreads();
    float mean_all  = (redA[0] + redA[1] + redA[2] + redA[3]) * (1.f / ((float)NNODE * (float)NNODE));
    float mean_diag = (redD[0] + redD[1] + redD[2] + redD[3]) * (1.f / (float)NNODE);
    float c3 = coeffs[3], c4c = coeffs[4];

    // --- per-graph vectors: one wave per section (was 3 serial 1-wave loops) ---
    if (wv == 0) {
        float a1 = 0.f;
        for (int d = 0; d < 64; ++d) a1 += mxs[d] * w12[e * 64 + d];
        pg1_l[e] = a1 + mean_diag * w15[e] + mean_all * w16[e];
    } else if (wv == 1) {
        float a2 = 0.f;
        for (int d = 0; d < 64; ++d) a2 += mxs[d] * w22[e * 64 + d];
        pg2_l[e] = a2 + mean_diag * w25[e] + mean_all * w26[e];
    } else if (wv == 2) {
        float v = wave_reduce(mxs[e] * wA2[e]);
        if (e == 0) p2s = v;
    } else {
        float rs  = rowsum[b * NNODE + i0 + e];
        float dgv = diagv[b * NNODE + i0 + e];
        float rmv = rs * (1.f / (float)NNODE);
        rm_l[e] = rmv;
        dg_l[e] = dgv;
        float rv = c3 * rmv + c4c * dgv + p1g[b * NNODE + i0 + e];
        r_l[e] = rv;
        rws[b * NNODE + i0 + e] = rv;
    }
    __syncthreads();
    if (tile == 0 && tid == 0)
        sArr[b] = coeffs[1] * mean_all + coeffs[2] * mean_diag + p2s;

    float w13e = w13[e], w14e = w14[e], w23e = w23[e], w24e = w24[e];
    float pg1e = pg1_l[e], pg2e = pg2_l[e];

    float acc1[16], acc2[16];
    #pragma unroll
    for (int t = 0; t < 16; ++t) { acc1[t] = 0.f; acc2[t] = 0.f; }

    for (int d0 = 0; d0 < 64; d0 += 4) {
        float4 w1v = *(const float4*)&w1l[e][d0];
        float4 w2v = *(const float4*)&w2l[e][d0];
        #pragma unroll
        for (int t = 0; t < 16; ++t) {
            int li = wv + 4 * t;
            float4 xv = *(const float4*)&Xl[li][d0];
            acc1[t] += xv.x * w1v.x + xv.y * w1v.y + xv.z * w1v.z + xv.w * w1v.w;
            acc2[t] += xv.x * w2v.x + xv.y * w2v.y + xv.z * w2v.z + xv.w * w2v.w;
        }
    }

    float s2acc = 0.f, r2acc = 0.f;
    #pragma unroll
    for (int t = 0; t < 16; ++t) {
        int li = wv + 4 * t;
        int i  = i0 + li;
        float rmv = rm_l[li], dgv = dg_l[li];
        float x2t = acc2[t] + rmv * w23e + dgv * w24e + pg2e;
        float b0  = acc1[t] + rmv * w13e + dgv * w14e + pg1e;
        base0[((size_t)(b * NNODE + i)) * 64 + e] = b0;
        X2Tl[e][li] = f2bf(x2t);
        s2acc += x2t;
        r2acc += r_l[li] * x2t;
    }
    redS[wv][e] = s2acc;
    redR[wv][e] = r2acc;
    __syncthreads();

    for (int k = 0; k < 16; ++k) {
        int ep = wv * 16 + k;
        unsigned short v = X2Tl[ep][e];
        x2tg[((size_t)(b * 64 + ep)) * NNODE + i0 + e] = v;
    }
    if (tid < 64) {
        float s2 = redS[0][tid] + redS[1][tid] + redS[2][tid] + redS[3][tid];
        float r2 = redR[0][tid] + redR[1][tid] + redR[2][tid] + redR[3][tid];
        S2part[(b * 16 + tile) * 64 + tid] = s2;
        R2part[(b * 16 + tile) * 64 + tid] = r2;
    }
}

// ---------------- kC: fused A_t + bf16 MFMA c0*(A @ X2t) + epilogue ----------------
// R4 structure (LDS-staged A, double-buffered, B from L2-resident ws) with:
//  - lgkm-only barrier (inline asm): At stores are fire-and-forget, no vmcnt(0)
//    drain per K-iter
//  - A-tile global loads software-pipelined one kt ahead
//  - NEW: B fragments also pipelined one kt ahead (L2 latency off critical path)
//  - NEW: v_cvt_pk_bf16_f32 pack (4 instrs vs ~32 VALU per kt)
//  - NEW: nontemporal At/out stores + base0 load (keep A L3-resident)
//  - LDS row stride 132 ushorts (66 words -> 2-way bank aliasing = free)
__global__ __launch_bounds__(256) void kC_main(const float* __restrict__ A,
                                               const float* __restrict__ coeffs,
                                               const float* __restrict__ sArr,
                                               const float* __restrict__ rArr,
                                               const unsigned short* __restrict__ x2tg,
                                               const float* __restrict__ base0,
                                               const float* __restrict__ S2part,
                                               const float* __restrict__ R2part,
                                               float* __restrict__ At,
                                               float* __restrict__ outp) {
    __shared__ unsigned short Al[2][16][132];
    __shared__ float r_lds[1024];
    __shared__ float s2_lds[64], r2_lds[64];

    int b    = blockIdx.x >> 6;      // 64 tiles of 16 rows per graph
    int tile = blockIdx.x & 63;
    int i0   = tile * 16;
    int tid  = threadIdx.x;

    // stage r (1024 floats); threads<64 also reduce S2/R2 partials
    float4 rv = ((const float4*)(rArr + b * NNODE))[tid];
    *(float4*)&r_lds[tid * 4] = rv;
    if (tid < 64) {
        float s2 = 0.f, r2 = 0.f;
        #pragma unroll
        for (int t = 0; t < 16; ++t) {
            s2 += S2part[(b * 16 + t) * 64 + tid];
            r2 += R2part[(b * 16 + t) * 64 + tid];
        }
        s2_lds[tid] = s2 * (1.f / (float)NNODE);
        r2_lds[tid] = r2 * (1.f / (float)NNODE);
    }

    float sb  = sArr[b];
    float c0  = coeffs[0];
    float c0n = c0 * (1.f / (float)NNODE);

    int arow = tid >> 4;             // 0..15
    int acol = (tid & 15) * 8;       // 0..120
    const float* Ab  = A  + ((size_t)(b * NNODE + i0 + arow)) * NNODE + acol;
    float*       Atb = At + ((size_t)(b * NNODE + i0 + arow)) * NNODE + acol;

    int lane = tid & 63, wv = tid >> 6;    // wv 0..3
    int m = lane & 15, quad = lane >> 4;
    int e = wv * 16 + m;
    const unsigned short* Bg = x2tg + ((size_t)(b * 64 + e)) * NNODE + quad * 8;

    // prefetch kt=0 A-tile into registers (no barrier dependency)
    float4 a0 = *(const float4*)(Ab);
    float4 a1 = *(const float4*)(Ab + 4);
    // prefetch kt=0 B fragments
    bf16x8 bf0 = *(const bf16x8*)(Bg);
    bf16x8 bf1 = *(const bf16x8*)(Bg + 32);
    bf16x8 bf2 = *(const bf16x8*)(Bg + 64);
    bf16x8 bf3 = *(const bf16x8*)(Bg + 96);

    f32x4 acc = {0.f, 0.f, 0.f, 0.f};

    __syncthreads();   // full barrier, once: r_lds / s2_lds ready

    float bse = sb + r_lds[i0 + arow];

    #pragma unroll
    for (int kt = 0; kt < 8; ++kt) {
        // ---- A_t compute + NT store (fire-and-forget) + bf16 pack into LDS ----
        int cidx = kt * 128 + acol;
        float4 rj0 = *(const float4*)&r_lds[cidx];
        float4 rj1 = *(const float4*)&r_lds[cidx + 4];
        f32x4 t0, t1;
        t0.x = fmaf(c0, a0.x, bse + rj0.x);
        t0.y = fmaf(c0, a0.y, bse + rj0.y);
        t0.z = fmaf(c0, a0.z, bse + rj0.z);
        t0.w = fmaf(c0, a0.w, bse + rj0.w);
        t1.x = fmaf(c0, a1.x, bse + rj1.x);
        t1.y = fmaf(c0, a1.y, bse + rj1.y);
        t1.z = fmaf(c0, a1.z, bse + rj1.z);
        t1.w = fmaf(c0, a1.w, bse + rj1.w);
        __builtin_nontemporal_store(t0, (f32x4*)(Atb + kt * 128));
        __builtin_nontemporal_store(t1, (f32x4*)(Atb + kt * 128 + 4));

        uint4 pk;
        pk.x = cvt_pk_bf16(a0.x, a0.y);
        pk.y = cvt_pk_bf16(a0.z, a0.w);
        pk.z = cvt_pk_bf16(a1.x, a1.y);
        pk.w = cvt_pk_bf16(a1.z, a1.w);
        *(uint4*)&Al[kt & 1][arow][acol] = pk;

        // ---- prefetch next kt's A-tile and B fragments (land after the barrier) ----
        bf16x8 n0, n1, n2, n3;
        if (kt < 7) {
            a0 = *(const float4*)(Ab + (kt + 1) * 128);
            a1 = *(const float4*)(Ab + (kt + 1) * 128 + 4);
            n0 = *(const bf16x8*)(Bg + (kt + 1) * 128);
            n1 = *(const bf16x8*)(Bg + (kt + 1) * 128 + 32);
            n2 = *(const bf16x8*)(Bg + (kt + 1) * 128 + 64);
            n3 = *(const bf16x8*)(Bg + (kt + 1) * 128 + 96);
        }

        // ---- lgkm-only barrier: LDS writes visible; NO vmcnt drain ----
        asm volatile("s_waitcnt lgkmcnt(0)\n\ts_barrier" ::: "memory");

        // ---- MFMA: 4 K-steps of 32 ----
        bf16x8 av0 = *(const bf16x8*)&Al[kt & 1][m][quad * 8];
        bf16x8 av1 = *(const bf16x8*)&Al[kt & 1][m][32 + quad * 8];
        bf16x8 av2 = *(const bf16x8*)&Al[kt & 1][m][64 + quad * 8];
        bf16x8 av3 = *(const bf16x8*)&Al[kt & 1][m][96 + quad * 8];
        acc = __builtin_amdgcn_mfma_f32_16x16x32_bf16(av0, bf0, acc, 0, 0, 0);
        acc = __builtin_amdgcn_mfma_f32_16x16x32_bf16(av1, bf1, acc, 0, 0, 0);
        acc = __builtin_amdgcn_mfma_f32_16x16x32_bf16(av2, bf2, acc, 0, 0, 0);
        acc = __builtin_amdgcn_mfma_f32_16x16x32_bf16(av3, bf3, acc, 0, 0, 0);

        if (kt < 7) { bf0 = n0; bf1 = n1; bf2 = n2; bf3 = n3; }
    }

    // ---- epilogue: out = c0/n * (A@X2t) + base0 + (s + r_i)*S2/n + R2/n ----
    float s2 = s2_lds[e];
    float r2 = r2_lds[e];
    #pragma unroll
    for (int reg = 0; reg < 4; ++reg) {
        int i = i0 + quad * 4 + reg;
        float bval = __builtin_nontemporal_load(base0 + ((size_t)(b * NNODE + i)) * 64 + e);
        float v = acc[reg] * c0n + bval + (sb + r_lds[i]) * s2 + r2;
        __builtin_nontemporal_store(v, outp + ((size_t)(b * NNODE + i)) * 64 + e);
    }
}

extern "C" void kernel_launch(void* const* d_in, const int* in_sizes, int n_in,
                              void* d_out, int out_size, void* d_ws, size_t ws_size,
                              hipStream_t stream) {
    const float* A      = (const float*)d_in[0];
    const float* X      = (const float*)d_in[1];
    const float* coeffs = (const float*)d_in[2];
    const float* wA1    = (const float*)d_in[3];
    const float* wA2    = (const float*)d_in[4];
    const float* w11    = (const float*)d_in[5];
    const float* w12    = (const float*)d_in[6];
    const float* w13    = (const float*)d_in[7];
    const float* w14    = (const float*)d_in[8];
    const float* w15    = (const float*)d_in[9];
    const float* w16    = (const float*)d_in[10];
    const float* w21    = (const float*)d_in[11];
    const float* w22    = (const float*)d_in[12];
    const float* w23    = (const float*)d_in[13];
    const float* w24    = (const float*)d_in[14];
    const float* w25    = (const float*)d_in[15];
    const float* w26    = (const float*)d_in[16];

    float* ws  = (float*)d_ws;
    float* At  = (float*)d_out;
    float* out = (float*)d_out + (size_t)NGRAPH * NNODE * NNODE;

    float* rowsum = ws + OFF_ROWSUM;
    float* diagv  = ws + OFF_DIAG;
    float* p1     = ws + OFF_P1;
    float* rws    = ws + OFF_R;
    float* cspart = ws + OFF_CS;
    float* sArr   = ws + OFF_S;
    float* S2part = ws + OFF_S2P;
    float* R2part = ws + OFF_R2P;
    float* base0  = ws + OFF_BASE0;
    unsigned short* x2tg = (unsigned short*)(ws + OFF_X2T);

    kA_stats<<<NGRAPH * NNODE / 4 + NGRAPH * 8, 256, 0, stream>>>(
        A, X, wA1, rowsum, diagv, p1, cspart);
    kB_nodes<<<NGRAPH * 16, 256, 0, stream>>>(
        X, coeffs, wA2, w11, w12, w13, w14, w15, w16,
        w21, w22, w23, w24, w25, w26,
        rowsum, diagv, cspart, p1,
        rws, base0, x2tg, S2part, R2part, sArr);
    kC_main<<<NGRAPH * 64, 256, 0, stream>>>(
        A, coeffs, sArr, rws, x2tg, base0, S2part, R2part, At, out);
}

// Round 2
// 205.319 us; speedup vs baseline: 1.0466x; 1.0466x over previous
//
#include <hip/hip_runtime.h>
#include <hip/hip_bf16.h>

#define NGRAPH 16
#define NNODE 1024
#define DDIM 64

typedef __attribute__((ext_vector_type(8))) short bf16x8;
typedef __attribute__((ext_vector_type(4))) float f32x4;

// ---- workspace layout (float offsets) ----
#define OFF_ROWSUM 0            // 16384
#define OFF_DIAG   16384        // 16384
#define OFF_P1     32768        // 16384
#define OFF_R      49152        // 16384
#define OFF_CS     65536        // 16*8*64 = 8192
#define OFF_S      73728        // 16 (+ pad)
#define OFF_S2P    75840        // 16384
#define OFF_R2P    92224        // 16384
#define OFF_BASE0  110656       // 16*1024*64 = 1048576
#define OFF_X2T    1159232      // ushort area: 16*64*1024 ushorts = 524288 floats

__device__ __forceinline__ unsigned short f2bf(float f) {
    unsigned int u = __float_as_uint(f);
    u = (u + 0x7fffu + ((u >> 16) & 1u)) >> 16;
    return (unsigned short)u;
}

// single-instruction packed f32->bf16 (RNE, same rounding as f2bf)
__device__ __forceinline__ unsigned int cvt_pk_bf16(float lo, float hi) {
    unsigned int r;
    asm("v_cvt_pk_bf16_f32 %0, %1, %2" : "=v"(r) : "v"(lo), "v"(hi));
    return r;
}

__device__ __forceinline__ float wave_reduce(float v) {
    #pragma unroll
    for (int off = 32; off; off >>= 1) v += __shfl_down(v, off, 64);
    return v;
}

// ---------------- kA: A row sums + diag  |  X column sums + p1 = X @ wA1 ----------------
__global__ __launch_bounds__(256) void kA_stats(const float* __restrict__ A,
                                                const float* __restrict__ X,
                                                const float* __restrict__ wA1,
                                                float* __restrict__ rowsum,
                                                float* __restrict__ diagv,
                                                float* __restrict__ p1,
                                                float* __restrict__ colsum_part) {
    if (blockIdx.x < NGRAPH * NNODE / 4) {
        int row  = blockIdx.x * 4 + (threadIdx.x >> 6);
        int lane = threadIdx.x & 63;
        const float4* b4 = (const float4*)(A + (size_t)row * NNODE);
        float sum = 0.f;
        #pragma unroll
        for (int it = 0; it < 4; ++it) {
            float4 v = b4[lane + it * 64];
            sum += v.x + v.y + v.z + v.w;
        }
        sum = wave_reduce(sum);
        if (lane == 0) {
            rowsum[row] = sum;
            int i = row & (NNODE - 1);
            diagv[row] = ((const float*)b4)[i];
        }
    } else {
        int bid  = blockIdx.x - NGRAPH * NNODE / 4;
        int b    = bid >> 3;
        int blk  = bid & 7;
        int wv   = threadIdx.x >> 6;
        int lane = threadIdx.x & 63;
        float w = wA1[lane];
        float cs = 0.f;
        int row0 = blk * 128 + wv * 32;
        const float* Xb = X + (size_t)b * NNODE * DDIM;
        for (int rI = 0; rI < 32; ++rI) {
            int i = row0 + rI;
            float x = Xb[i * DDIM + lane];
            cs += x;
            float v = wave_reduce(x * w);
            if (lane == 0) p1[b * NNODE + i] = v;
        }
        __shared__ float csl[4][64];
        csl[wv][lane] = cs;
        __syncthreads();
        if (threadIdx.x < 64) {
            float t = csl[0][lane] + csl[1][lane] + csl[2][lane] + csl[3][lane];
            colsum_part[(b * 8 + blk) * 64 + lane] = t;
        }
    }
}

// ---------------- kB: per-graph stats (recomputed per block) + per-node transforms ----------------
__global__ __launch_bounds__(256) void kB_nodes(const float* __restrict__ X,
                                                const float* __restrict__ coeffs,
                                                const float* __restrict__ wA2,
                                                const float* __restrict__ w11,
                                                const float* __restrict__ w12,
                                                const float* __restrict__ w13,
                                                const float* __restrict__ w14,
                                                const float* __restrict__ w15,
                                                const float* __restrict__ w16,
                                                const float* __restrict__ w21,
                                                const float* __restrict__ w22,
                                                const float* __restrict__ w23,
                                                const float* __restrict__ w24,
                                                const float* __restrict__ w25,
                                                const float* __restrict__ w26,
                                                const float* __restrict__ rowsum,
                                                const float* __restrict__ diagv,
                                                const float* __restrict__ colsum_part,
                                                const float* __restrict__ p1g,
                                                float* __restrict__ rws,
                                                float* __restrict__ base0,
                                                unsigned short* __restrict__ x2tg,
                                                float* __restrict__ S2part,
                                                float* __restrict__ R2part,
                                                float* __restrict__ sArr) {
    __shared__ float Xl[64][68];
    __shared__ float w1l[64][68];
    __shared__ float w2l[64][68];
    __shared__ unsigned short X2Tl[64][68];
    __shared__ float rm_l[64], dg_l[64], r_l[64];
    __shared__ float redS[4][64], redR[4][64];
    __shared__ float redA[4], redD[4];
    __shared__ float mxs[64], p2s;
    __shared__ float pg1_l[64], pg2_l[64];

    int b    = blockIdx.x >> 4;
    int tile = blockIdx.x & 15;
    int i0   = tile * 64;
    int tid  = threadIdx.x;
    int e    = tid & 63;
    int wv   = tid >> 6;

    // --- stage X tile + weights ---
    const float* Xg = X + (size_t)b * (NNODE * DDIM) + (size_t)i0 * DDIM;
    #pragma unroll
    for (int it = 0; it < 4; ++it) {
        int g   = it * 256 + tid;
        int row = g >> 4;
        int c4  = (g & 15) << 2;
        float4 v  = ((const float4*)Xg)[g];
        *(float4*)&Xl[row][c4] = v;
        float4 v1 = ((const float4*)w11)[g];
        *(float4*)&w1l[row][c4] = v1;
        float4 v2 = ((const float4*)w21)[g];
        *(float4*)&w2l[row][c4] = v2;
    }

    // --- per-graph scalar stats (every block recomputes; cheap) ---
    float sa = 0.f, sd = 0.f;
    for (int i = tid; i < NNODE; i += 256) {
        sa += rowsum[b * NNODE + i];
        sd += diagv[b * NNODE + i];
    }
    sa = wave_reduce(sa); sd = wave_reduce(sd);
    if (e == 0) { redA[wv] = sa; redD[wv] = sd; }
    if (tid < 64) {
        float mx = 0.f;
        for (int k = 0; k < 8; ++k) mx += colsum_part[(b * 8 + k) * 64 + tid];
        mxs[tid] = mx * (1.f / (float)NNODE);
    }
    __syncthreads();
    float mean_all  = (redA[0] + redA[1] + redA[2] + redA[3]) * (1.f / ((float)NNODE * (float)NNODE));
    float mean_diag = (redD[0] + redD[1] + redD[2] + redD[3]) * (1.f / (float)NNODE);
    float c3 = coeffs[3], c4c = coeffs[4];

    // --- per-graph vectors: one wave per section (concurrent, not serial) ---
    if (wv == 0) {
        float a1 = 0.f;
        for (int d = 0; d < 64; ++d) a1 += mxs[d] * w12[e * 64 + d];
        pg1_l[e] = a1 + mean_diag * w15[e] + mean_all * w16[e];
    } else if (wv == 1) {
        float a2 = 0.f;
        for (int d = 0; d < 64; ++d) a2 += mxs[d] * w22[e * 64 + d];
        pg2_l[e] = a2 + mean_diag * w25[e] + mean_all * w26[e];
    } else if (wv == 2) {
        float v = wave_reduce(mxs[e] * wA2[e]);
        if (e == 0) p2s = v;
    } else {
        float rs  = rowsum[b * NNODE + i0 + e];
        float dgv = diagv[b * NNODE + i0 + e];
        float rmv = rs * (1.f / (float)NNODE);
        rm_l[e] = rmv;
        dg_l[e] = dgv;
        float rv = c3 * rmv + c4c * dgv + p1g[b * NNODE + i0 + e];
        r_l[e] = rv;
        rws[b * NNODE + i0 + e] = rv;
    }
    __syncthreads();
    if (tile == 0 && tid == 0)
        sArr[b] = coeffs[1] * mean_all + coeffs[2] * mean_diag + p2s;

    float w13e = w13[e], w14e = w14[e], w23e = w23[e], w24e = w24[e];
    float pg1e = pg1_l[e], pg2e = pg2_l[e];

    float acc1[16], acc2[16];
    #pragma unroll
    for (int t = 0; t < 16; ++t) { acc1[t] = 0.f; acc2[t] = 0.f; }

    for (int d0 = 0; d0 < 64; d0 += 4) {
        float4 w1v = *(const float4*)&w1l[e][d0];
        float4 w2v = *(const float4*)&w2l[e][d0];
        #pragma unroll
        for (int t = 0; t < 16; ++t) {
            int li = wv + 4 * t;
            float4 xv = *(const float4*)&Xl[li][d0];
            acc1[t] += xv.x * w1v.x + xv.y * w1v.y + xv.z * w1v.z + xv.w * w1v.w;
            acc2[t] += xv.x * w2v.x + xv.y * w2v.y + xv.z * w2v.z + xv.w * w2v.w;
        }
    }

    float s2acc = 0.f, r2acc = 0.f;
    #pragma unroll
    for (int t = 0; t < 16; ++t) {
        int li = wv + 4 * t;
        int i  = i0 + li;
        float rmv = rm_l[li], dgv = dg_l[li];
        float x2t = acc2[t] + rmv * w23e + dgv * w24e + pg2e;
        float b0  = acc1[t] + rmv * w13e + dgv * w14e + pg1e;
        base0[((size_t)(b * NNODE + i)) * 64 + e] = b0;
        X2Tl[e][li] = f2bf(x2t);
        s2acc += x2t;
        r2acc += r_l[li] * x2t;
    }
    redS[wv][e] = s2acc;
    redR[wv][e] = r2acc;
    __syncthreads();

    for (int k = 0; k < 16; ++k) {
        int ep = wv * 16 + k;
        unsigned short v = X2Tl[ep][e];
        x2tg[((size_t)(b * 64 + ep)) * NNODE + i0 + e] = v;
    }
    if (tid < 64) {
        float s2 = redS[0][tid] + redS[1][tid] + redS[2][tid] + redS[3][tid];
        float r2 = redR[0][tid] + redR[1][tid] + redR[2][tid] + redR[3][tid];
        S2part[(b * 16 + tile) * 64 + tid] = s2;
        R2part[(b * 16 + tile) * 64 + tid] = r2;
    }
}

// ---------------- kC: fused A_t + bf16 MFMA c0*(A @ X2t) + epilogue ----------------
// R4 structure (LDS-staged A, double-buffered, B from L2-resident ws) with:
//  - lgkm-only barrier (inline asm): At stores are fire-and-forget, no vmcnt(0)
//    drain per K-iter
//  - A-tile global loads software-pipelined one kt ahead
//  - B fragments also pipelined one kt ahead (L2 latency off critical path)
//  - v_cvt_pk_bf16_f32 pack (4 instrs vs ~32 VALU per kt)
//  - NT stores REVERTED (round-1 post-mortem: 2x write amplification on At,
//    WRITE_SIZE 118 MB vs 70 MB ideal -- the 16B-store/32B-stride pattern
//    needs L2 write-back merging)
//  - LDS row stride 132 ushorts (66 words -> 2-way bank aliasing = free)
__global__ __launch_bounds__(256) void kC_main(const float* __restrict__ A,
                                               const float* __restrict__ coeffs,
                                               const float* __restrict__ sArr,
                                               const float* __restrict__ rArr,
                                               const unsigned short* __restrict__ x2tg,
                                               const float* __restrict__ base0,
                                               const float* __restrict__ S2part,
                                               const float* __restrict__ R2part,
                                               float* __restrict__ At,
                                               float* __restrict__ outp) {
    __shared__ unsigned short Al[2][16][132];
    __shared__ float r_lds[1024];
    __shared__ float s2_lds[64], r2_lds[64];

    int b    = blockIdx.x >> 6;      // 64 tiles of 16 rows per graph
    int tile = blockIdx.x & 63;
    int i0   = tile * 16;
    int tid  = threadIdx.x;

    // stage r (1024 floats); threads<64 also reduce S2/R2 partials
    float4 rv = ((const float4*)(rArr + b * NNODE))[tid];
    *(float4*)&r_lds[tid * 4] = rv;
    if (tid < 64) {
        float s2 = 0.f, r2 = 0.f;
        #pragma unroll
        for (int t = 0; t < 16; ++t) {
            s2 += S2part[(b * 16 + t) * 64 + tid];
            r2 += R2part[(b * 16 + t) * 64 + tid];
        }
        s2_lds[tid] = s2 * (1.f / (float)NNODE);
        r2_lds[tid] = r2 * (1.f / (float)NNODE);
    }

    float sb  = sArr[b];
    float c0  = coeffs[0];
    float c0n = c0 * (1.f / (float)NNODE);

    int arow = tid >> 4;             // 0..15
    int acol = (tid & 15) * 8;       // 0..120
    const float* Ab  = A  + ((size_t)(b * NNODE + i0 + arow)) * NNODE + acol;
    float*       Atb = At + ((size_t)(b * NNODE + i0 + arow)) * NNODE + acol;

    int lane = tid & 63, wv = tid >> 6;    // wv 0..3
    int m = lane & 15, quad = lane >> 4;
    int e = wv * 16 + m;
    const unsigned short* Bg = x2tg + ((size_t)(b * 64 + e)) * NNODE + quad * 8;

    // prefetch kt=0 A-tile into registers (no barrier dependency)
    float4 a0 = *(const float4*)(Ab);
    float4 a1 = *(const float4*)(Ab + 4);
    // prefetch kt=0 B fragments
    bf16x8 bf0 = *(const bf16x8*)(Bg);
    bf16x8 bf1 = *(const bf16x8*)(Bg + 32);
    bf16x8 bf2 = *(const bf16x8*)(Bg + 64);
    bf16x8 bf3 = *(const bf16x8*)(Bg + 96);

    f32x4 acc = {0.f, 0.f, 0.f, 0.f};

    __syncthreads();   // full barrier, once: r_lds / s2_lds ready

    float bse = sb + r_lds[i0 + arow];

    #pragma unroll
    for (int kt = 0; kt < 8; ++kt) {
        // ---- A_t compute + store (fire-and-forget) + bf16 pack into LDS ----
        int cidx = kt * 128 + acol;
        float4 rj0 = *(const float4*)&r_lds[cidx];
        float4 rj1 = *(const float4*)&r_lds[cidx + 4];
        f32x4 t0, t1;
        t0.x = fmaf(c0, a0.x, bse + rj0.x);
        t0.y = fmaf(c0, a0.y, bse + rj0.y);
        t0.z = fmaf(c0, a0.z, bse + rj0.z);
        t0.w = fmaf(c0, a0.w, bse + rj0.w);
        t1.x = fmaf(c0, a1.x, bse + rj1.x);
        t1.y = fmaf(c0, a1.y, bse + rj1.y);
        t1.z = fmaf(c0, a1.z, bse + rj1.z);
        t1.w = fmaf(c0, a1.w, bse + rj1.w);
        *(f32x4*)(Atb + kt * 128)     = t0;
        *(f32x4*)(Atb + kt * 128 + 4) = t1;

        uint4 pk;
        pk.x = cvt_pk_bf16(a0.x, a0.y);
        pk.y = cvt_pk_bf16(a0.z, a0.w);
        pk.z = cvt_pk_bf16(a1.x, a1.y);
        pk.w = cvt_pk_bf16(a1.z, a1.w);
        *(uint4*)&Al[kt & 1][arow][acol] = pk;

        // ---- prefetch next kt's A-tile and B fragments (land after the barrier) ----
        bf16x8 n0, n1, n2, n3;
        if (kt < 7) {
            a0 = *(const float4*)(Ab + (kt + 1) * 128);
            a1 = *(const float4*)(Ab + (kt + 1) * 128 + 4);
            n0 = *(const bf16x8*)(Bg + (kt + 1) * 128);
            n1 = *(const bf16x8*)(Bg + (kt + 1) * 128 + 32);
            n2 = *(const bf16x8*)(Bg + (kt + 1) * 128 + 64);
            n3 = *(const bf16x8*)(Bg + (kt + 1) * 128 + 96);
        }

        // ---- lgkm-only barrier: LDS writes visible; NO vmcnt drain ----
        asm volatile("s_waitcnt lgkmcnt(0)\n\ts_barrier" ::: "memory");

        // ---- MFMA: 4 K-steps of 32 ----
        bf16x8 av0 = *(const bf16x8*)&Al[kt & 1][m][quad * 8];
        bf16x8 av1 = *(const bf16x8*)&Al[kt & 1][m][32 + quad * 8];
        bf16x8 av2 = *(const bf16x8*)&Al[kt & 1][m][64 + quad * 8];
        bf16x8 av3 = *(const bf16x8*)&Al[kt & 1][m][96 + quad * 8];
        acc = __builtin_amdgcn_mfma_f32_16x16x32_bf16(av0, bf0, acc, 0, 0, 0);
        acc = __builtin_amdgcn_mfma_f32_16x16x32_bf16(av1, bf1, acc, 0, 0, 0);
        acc = __builtin_amdgcn_mfma_f32_16x16x32_bf16(av2, bf2, acc, 0, 0, 0);
        acc = __builtin_amdgcn_mfma_f32_16x16x32_bf16(av3, bf3, acc, 0, 0, 0);

        if (kt < 7) { bf0 = n0; bf1 = n1; bf2 = n2; bf3 = n3; }
    }

    // ---- epilogue: out = c0/n * (A@X2t) + base0 + (s + r_i)*S2/n + R2/n ----
    float s2 = s2_lds[e];
    float r2 = r2_lds[e];
    #pragma unroll
    for (int reg = 0; reg < 4; ++reg) {
        int i = i0 + quad * 4 + reg;
        float v = acc[reg] * c0n
                + base0[((size_t)(b * NNODE + i)) * 64 + e]
                + (sb + r_lds[i]) * s2 + r2;
        outp[((size_t)(b * NNODE + i)) * 64 + e] = v;
    }
}

extern "C" void kernel_launch(void* const* d_in, const int* in_sizes, int n_in,
                              void* d_out, int out_size, void* d_ws, size_t ws_size,
                              hipStream_t stream) {
    const float* A      = (const float*)d_in[0];
    const float* X      = (const float*)d_in[1];
    const float* coeffs = (const float*)d_in[2];
    const float* wA1    = (const float*)d_in[3];
    const float* wA2    = (const float*)d_in[4];
    const float* w11    = (const float*)d_in[5];
    const float* w12    = (const float*)d_in[6];
    const float* w13    = (const float*)d_in[7];
    const float* w14    = (const float*)d_in[8];
    const float* w15    = (const float*)d_in[9];
    const float* w16    = (const float*)d_in[10];
    const float* w21    = (const float*)d_in[11];
    const float* w22    = (const float*)d_in[12];
    const float* w23    = (const float*)d_in[13];
    const float* w24    = (const float*)d_in[14];
    const float* w25    = (const float*)d_in[15];
    const float* w26    = (const float*)d_in[16];

    float* ws  = (float*)d_ws;
    float* At  = (float*)d_out;
    float* out = (float*)d_out + (size_t)NGRAPH * NNODE * NNODE;

    float* rowsum = ws + OFF_ROWSUM;
    float* diagv  = ws + OFF_DIAG;
    float* p1     = ws + OFF_P1;
    float* rws    = ws + OFF_R;
    float* cspart = ws + OFF_CS;
    float* sArr   = ws + OFF_S;
    float* S2part = ws + OFF_S2P;
    float* R2part = ws + OFF_R2P;
    float* base0  = ws + OFF_BASE0;
    unsigned short* x2tg = (unsigned short*)(ws + OFF_X2T);

    kA_stats<<<NGRAPH * NNODE / 4 + NGRAPH * 8, 256, 0, stream>>>(
        A, X, wA1, rowsum, diagv, p1, cspart);
    kB_nodes<<<NGRAPH * 16, 256, 0, stream>>>(
        X, coeffs, wA2, w11, w12, w13, w14, w15, w16,
        w21, w22, w23, w24, w25, w26,
        rowsum, diagv, cspart, p1,
        rws, base0, x2tg, S2part, R2part, sArr);
    kC_main<<<NGRAPH * 64, 256, 0, stream>>>(
        A, coeffs, sArr, rws, x2tg, base0, S2part, R2part, At, out);
}

// Round 3
// 203.608 us; speedup vs baseline: 1.0554x; 1.0084x over previous
//
#include <hip/hip_runtime.h>
#include <hip/hip_bf16.h>

#define NGRAPH 16
#define NNODE 1024
#define DDIM 64

typedef __attribute__((ext_vector_type(8))) short bf16x8;
typedef __attribute__((ext_vector_type(4))) float f32x4;

// ---- workspace layout (float offsets) ----
#define OFF_ROWSUM 0            // 16384
#define OFF_DIAG   16384        // 16384
#define OFF_P1     32768        // 16384
#define OFF_R      49152        // 16384
#define OFF_CS     65536        // 16*8*64 = 8192
#define OFF_S      73728        // 16 (+ pad)
#define OFF_S2P    75840        // 16384
#define OFF_R2P    92224        // 16384
#define OFF_BASE0  110656       // 16*1024*64 = 1048576
#define OFF_X2T    1159232      // ushort area: 16*64*1024 ushorts = 524288 floats

__device__ __forceinline__ unsigned short f2bf(float f) {
    unsigned int u = __float_as_uint(f);
    u = (u + 0x7fffu + ((u >> 16) & 1u)) >> 16;
    return (unsigned short)u;
}

// single-instruction packed f32->bf16 (RNE, same rounding as f2bf)
__device__ __forceinline__ unsigned int cvt_pk_bf16(float lo, float hi) {
    unsigned int r;
    asm("v_cvt_pk_bf16_f32 %0, %1, %2" : "=v"(r) : "v"(lo), "v"(hi));
    return r;
}

__device__ __forceinline__ float wave_reduce(float v) {
    #pragma unroll
    for (int off = 32; off; off >>= 1) v += __shfl_down(v, off, 64);
    return v;
}

// ---------------- kA: A row sums + diag  |  X column sums + p1 = X @ wA1 ----------------
__global__ __launch_bounds__(256) void kA_stats(const float* __restrict__ A,
                                                const float* __restrict__ X,
                                                const float* __restrict__ wA1,
                                                float* __restrict__ rowsum,
                                                float* __restrict__ diagv,
                                                float* __restrict__ p1,
                                                float* __restrict__ colsum_part) {
    if (blockIdx.x < NGRAPH * NNODE / 4) {
        int row  = blockIdx.x * 4 + (threadIdx.x >> 6);
        int lane = threadIdx.x & 63;
        const float4* b4 = (const float4*)(A + (size_t)row * NNODE);
        float sum = 0.f;
        #pragma unroll
        for (int it = 0; it < 4; ++it) {
            float4 v = b4[lane + it * 64];
            sum += v.x + v.y + v.z + v.w;
        }
        sum = wave_reduce(sum);
        if (lane == 0) {
            rowsum[row] = sum;
            int i = row & (NNODE - 1);
            diagv[row] = ((const float*)b4)[i];
        }
    } else {
        int bid  = blockIdx.x - NGRAPH * NNODE / 4;
        int b    = bid >> 3;
        int blk  = bid & 7;
        int wv   = threadIdx.x >> 6;
        int lane = threadIdx.x & 63;
        float w = wA1[lane];
        float cs = 0.f;
        int row0 = blk * 128 + wv * 32;
        const float* Xb = X + (size_t)b * NNODE * DDIM;
        for (int rI = 0; rI < 32; ++rI) {
            int i = row0 + rI;
            float x = Xb[i * DDIM + lane];
            cs += x;
            float v = wave_reduce(x * w);
            if (lane == 0) p1[b * NNODE + i] = v;
        }
        __shared__ float csl[4][64];
        csl[wv][lane] = cs;
        __syncthreads();
        if (threadIdx.x < 64) {
            float t = csl[0][lane] + csl[1][lane] + csl[2][lane] + csl[3][lane];
            colsum_part[(b * 8 + blk) * 64 + lane] = t;
        }
    }
}

// ---------------- kB: per-graph stats (recomputed per block) + per-node transforms ----------------
__global__ __launch_bounds__(256) void kB_nodes(const float* __restrict__ X,
                                                const float* __restrict__ coeffs,
                                                const float* __restrict__ wA2,
                                                const float* __restrict__ w11,
                                                const float* __restrict__ w12,
                                                const float* __restrict__ w13,
                                                const float* __restrict__ w14,
                                                const float* __restrict__ w15,
                                                const float* __restrict__ w16,
                                                const float* __restrict__ w21,
                                                const float* __restrict__ w22,
                                                const float* __restrict__ w23,
                                                const float* __restrict__ w24,
                                                const float* __restrict__ w25,
                                                const float* __restrict__ w26,
                                                const float* __restrict__ rowsum,
                                                const float* __restrict__ diagv,
                                                const float* __restrict__ colsum_part,
                                                const float* __restrict__ p1g,
                                                float* __restrict__ rws,
                                                float* __restrict__ base0,
                                                unsigned short* __restrict__ x2tg,
                                                float* __restrict__ S2part,
                                                float* __restrict__ R2part,
                                                float* __restrict__ sArr) {
    __shared__ float Xl[64][68];
    __shared__ float w1l[64][68];
    __shared__ float w2l[64][68];
    __shared__ unsigned short X2Tl[64][68];
    __shared__ float rm_l[64], dg_l[64], r_l[64];
    __shared__ float redS[4][64], redR[4][64];
    __shared__ float redA[4], redD[4];
    __shared__ float mxs[64], p2s;
    __shared__ float pg1_l[64], pg2_l[64];

    int b    = blockIdx.x >> 4;
    int tile = blockIdx.x & 15;
    int i0   = tile * 64;
    int tid  = threadIdx.x;
    int e    = tid & 63;
    int wv   = tid >> 6;

    // --- stage X tile + weights ---
    const float* Xg = X + (size_t)b * (NNODE * DDIM) + (size_t)i0 * DDIM;
    #pragma unroll
    for (int it = 0; it < 4; ++it) {
        int g   = it * 256 + tid;
        int row = g >> 4;
        int c4  = (g & 15) << 2;
        float4 v  = ((const float4*)Xg)[g];
        *(float4*)&Xl[row][c4] = v;
        float4 v1 = ((const float4*)w11)[g];
        *(float4*)&w1l[row][c4] = v1;
        float4 v2 = ((const float4*)w21)[g];
        *(float4*)&w2l[row][c4] = v2;
    }

    // --- per-graph scalar stats (every block recomputes; cheap) ---
    float sa = 0.f, sd = 0.f;
    for (int i = tid; i < NNODE; i += 256) {
        sa += rowsum[b * NNODE + i];
        sd += diagv[b * NNODE + i];
    }
    sa = wave_reduce(sa); sd = wave_reduce(sd);
    if (e == 0) { redA[wv] = sa; redD[wv] = sd; }
    if (tid < 64) {
        float mx = 0.f;
        for (int k = 0; k < 8; ++k) mx += colsum_part[(b * 8 + k) * 64 + tid];
        mxs[tid] = mx * (1.f / (float)NNODE);
    }
    __syncthreads();
    float mean_all  = (redA[0] + redA[1] + redA[2] + redA[3]) * (1.f / ((float)NNODE * (float)NNODE));
    float mean_diag = (redD[0] + redD[1] + redD[2] + redD[3]) * (1.f / (float)NNODE);
    float c3 = coeffs[3], c4c = coeffs[4];

    // --- per-graph vectors: one wave per section (concurrent, not serial) ---
    if (wv == 0) {
        float a1 = 0.f;
        for (int d = 0; d < 64; ++d) a1 += mxs[d] * w12[e * 64 + d];
        pg1_l[e] = a1 + mean_diag * w15[e] + mean_all * w16[e];
    } else if (wv == 1) {
        float a2 = 0.f;
        for (int d = 0; d < 64; ++d) a2 += mxs[d] * w22[e * 64 + d];
        pg2_l[e] = a2 + mean_diag * w25[e] + mean_all * w26[e];
    } else if (wv == 2) {
        float v = wave_reduce(mxs[e] * wA2[e]);
        if (e == 0) p2s = v;
    } else {
        float rs  = rowsum[b * NNODE + i0 + e];
        float dgv = diagv[b * NNODE + i0 + e];
        float rmv = rs * (1.f / (float)NNODE);
        rm_l[e] = rmv;
        dg_l[e] = dgv;
        float rv = c3 * rmv + c4c * dgv + p1g[b * NNODE + i0 + e];
        r_l[e] = rv;
        rws[b * NNODE + i0 + e] = rv;
    }
    __syncthreads();
    if (tile == 0 && tid == 0)
        sArr[b] = coeffs[1] * mean_all + coeffs[2] * mean_diag + p2s;

    float w13e = w13[e], w14e = w14[e], w23e = w23[e], w24e = w24[e];
    float pg1e = pg1_l[e], pg2e = pg2_l[e];

    float acc1[16], acc2[16];
    #pragma unroll
    for (int t = 0; t < 16; ++t) { acc1[t] = 0.f; acc2[t] = 0.f; }

    for (int d0 = 0; d0 < 64; d0 += 4) {
        float4 w1v = *(const float4*)&w1l[e][d0];
        float4 w2v = *(const float4*)&w2l[e][d0];
        #pragma unroll
        for (int t = 0; t < 16; ++t) {
            int li = wv + 4 * t;
            float4 xv = *(const float4*)&Xl[li][d0];
            acc1[t] += xv.x * w1v.x + xv.y * w1v.y + xv.z * w1v.z + xv.w * w1v.w;
            acc2[t] += xv.x * w2v.x + xv.y * w2v.y + xv.z * w2v.z + xv.w * w2v.w;
        }
    }

    float s2acc = 0.f, r2acc = 0.f;
    #pragma unroll
    for (int t = 0; t < 16; ++t) {
        int li = wv + 4 * t;
        int i  = i0 + li;
        float rmv = rm_l[li], dgv = dg_l[li];
        float x2t = acc2[t] + rmv * w23e + dgv * w24e + pg2e;
        float b0  = acc1[t] + rmv * w13e + dgv * w14e + pg1e;
        base0[((size_t)(b * NNODE + i)) * 64 + e] = b0;
        X2Tl[e][li] = f2bf(x2t);
        s2acc += x2t;
        r2acc += r_l[li] * x2t;
    }
    redS[wv][e] = s2acc;
    redR[wv][e] = r2acc;
    __syncthreads();

    for (int k = 0; k < 16; ++k) {
        int ep = wv * 16 + k;
        unsigned short v = X2Tl[ep][e];
        x2tg[((size_t)(b * 64 + ep)) * NNODE + i0 + e] = v;
    }
    if (tid < 64) {
        float s2 = redS[0][tid] + redS[1][tid] + redS[2][tid] + redS[3][tid];
        float r2 = redR[0][tid] + redR[1][tid] + redR[2][tid] + redR[3][tid];
        S2part[(b * 16 + tile) * 64 + tid] = s2;
        R2part[(b * 16 + tile) * 64 + tid] = r2;
    }
}

// ---------------- kC: fused A_t + bf16 MFMA c0*(A @ X2t) + epilogue ----------------
// R3 RESTRUCTURE: barrier-free per-wave tiles.
//  - Each WAVE owns a 16-row tile and computes all 64 output cols (4 MFMA chains).
//  - A is loaded DIRECTLY in MFMA fragment layout: lane l reads 8 contiguous
//    floats of row i0+(l&15) at col ks*32+(l>>4)*8 (16 rows x 128B segments,
//    every byte used). No LDS transpose, no per-kt barriers, no lockstep.
//  - A_t computed from the same registers and stored (normal stores; L2 merges
//    the 16B/32B-stride partials -- round-1 lesson).
//  - cvt_pk_bf16 packs A in-register into the MFMA A-operand.
//  - A prefetched one kt ahead; 16 L2-resident B loads issued per kt
//    => ~24 outstanding mem ops per wave, waves fully independent after init.
__global__ __launch_bounds__(256) void kC_main(const float* __restrict__ A,
                                               const float* __restrict__ coeffs,
                                               const float* __restrict__ sArr,
                                               const float* __restrict__ rArr,
                                               const unsigned short* __restrict__ x2tg,
                                               const float* __restrict__ base0,
                                               const float* __restrict__ S2part,
                                               const float* __restrict__ R2part,
                                               float* __restrict__ At,
                                               float* __restrict__ outp) {
    __shared__ float r_lds[1024];
    __shared__ float s2_lds[64], r2_lds[64];

    int b    = blockIdx.x >> 4;      // 16 blocks per graph, 4 wave-tiles each
    int tb   = blockIdx.x & 15;
    int tid  = threadIdx.x;
    int lane = tid & 63, wv = tid >> 6;
    int i0   = (tb * 4 + wv) * 16;   // this wave's 16-row tile
    int m    = lane & 15, q = lane >> 4;

    // stage r (1024 floats); threads<64 also reduce S2/R2 partials
    float4 rv = ((const float4*)(rArr + b * NNODE))[tid];
    *(float4*)&r_lds[tid * 4] = rv;
    if (tid < 64) {
        float s2 = 0.f, r2 = 0.f;
        #pragma unroll
        for (int t = 0; t < 16; ++t) {
            s2 += S2part[(b * 16 + t) * 64 + tid];
            r2 += R2part[(b * 16 + t) * 64 + tid];
        }
        s2_lds[tid] = s2 * (1.f / (float)NNODE);
        r2_lds[tid] = r2 * (1.f / (float)NNODE);
    }

    float sb  = sArr[b];
    float c0  = coeffs[0];
    float c0n = c0 * (1.f / (float)NNODE);

    // per-lane fragment-layout pointers
    const float* Aw  = A  + ((size_t)(b * NNODE + i0 + m)) * NNODE + q * 8;
    float*       Atw = At + ((size_t)(b * NNODE + i0 + m)) * NNODE + q * 8;
    const unsigned short* Bw = x2tg + ((size_t)(b * 64 + m)) * NNODE + q * 8;

    // prefetch kt=0 A fragment (no LDS dependency -> issue before the barrier)
    f32x4 a[8], an[8];
    #pragma unroll
    for (int ks = 0; ks < 4; ++ks) {
        a[2 * ks]     = *(const f32x4*)(Aw + ks * 32);
        a[2 * ks + 1] = *(const f32x4*)(Aw + ks * 32 + 4);
    }

    f32x4 acc[4];
    #pragma unroll
    for (int s = 0; s < 4; ++s) acc[s] = (f32x4){0.f, 0.f, 0.f, 0.f};

    __syncthreads();   // once: r_lds / s2_lds ready; waves independent after this

    float bse = sb + r_lds[i0 + m];

    #pragma unroll 2
    for (int kt = 0; kt < 8; ++kt) {
        // ---- B fragments for this kt: all 4 output-col slices (L2-resident) ----
        bf16x8 Bf[4][4];
        #pragma unroll
        for (int s = 0; s < 4; ++s) {
            #pragma unroll
            for (int ks = 0; ks < 4; ++ks) {
                Bf[s][ks] = *(const bf16x8*)(Bw + (size_t)s * 16 * NNODE + kt * 128 + ks * 32);
            }
        }

        // ---- prefetch next kt's A fragment (lands during this kt's compute) ----
        if (kt < 7) {
            #pragma unroll
            for (int ks = 0; ks < 4; ++ks) {
                an[2 * ks]     = *(const f32x4*)(Aw + (kt + 1) * 128 + ks * 32);
                an[2 * ks + 1] = *(const f32x4*)(Aw + (kt + 1) * 128 + ks * 32 + 4);
            }
        }

        // ---- A_t compute + store (fire-and-forget) + in-register bf16 pack ----
        bf16x8 pka[4];
        #pragma unroll
        for (int ks = 0; ks < 4; ++ks) {
            int cb = kt * 128 + ks * 32 + q * 8;
            f32x4 rj0 = *(const f32x4*)&r_lds[cb];       // wave-broadcast reads
            f32x4 rj1 = *(const f32x4*)&r_lds[cb + 4];
            f32x4 ac0 = a[2 * ks], ac1 = a[2 * ks + 1];
            f32x4 t0, t1;
            t0.x = fmaf(c0, ac0.x, bse + rj0.x);
            t0.y = fmaf(c0, ac0.y, bse + rj0.y);
            t0.z = fmaf(c0, ac0.z, bse + rj0.z);
            t0.w = fmaf(c0, ac0.w, bse + rj0.w);
            t1.x = fmaf(c0, ac1.x, bse + rj1.x);
            t1.y = fmaf(c0, ac1.y, bse + rj1.y);
            t1.z = fmaf(c0, ac1.z, bse + rj1.z);
            t1.w = fmaf(c0, ac1.w, bse + rj1.w);
            *(f32x4*)(Atw + kt * 128 + ks * 32)     = t0;
            *(f32x4*)(Atw + kt * 128 + ks * 32 + 4) = t1;

            union { uint4 u; bf16x8 h; } cv;
            cv.u.x = cvt_pk_bf16(ac0.x, ac0.y);
            cv.u.y = cvt_pk_bf16(ac0.z, ac0.w);
            cv.u.z = cvt_pk_bf16(ac1.x, ac1.y);
            cv.u.w = cvt_pk_bf16(ac1.z, ac1.w);
            pka[ks] = cv.h;
        }

        // ---- 16 MFMAs: 4 output-col slices x 4 K-steps of 32 ----
        #pragma unroll
        for (int s = 0; s < 4; ++s) {
            #pragma unroll
            for (int ks = 0; ks < 4; ++ks) {
                acc[s] = __builtin_amdgcn_mfma_f32_16x16x32_bf16(pka[ks], Bf[s][ks], acc[s], 0, 0, 0);
            }
        }

        if (kt < 7) {
            #pragma unroll
            for (int u = 0; u < 8; ++u) a[u] = an[u];
        }
    }

    // ---- epilogue: out = c0/n * (A@X2t) + base0 + (s + r_i)*S2/n + R2/n ----
    #pragma unroll
    for (int s = 0; s < 4; ++s) {
        float s2 = s2_lds[s * 16 + m];
        float r2 = r2_lds[s * 16 + m];
        #pragma unroll
        for (int reg = 0; reg < 4; ++reg) {
            int i = i0 + q * 4 + reg;
            float v = acc[s][reg] * c0n
                    + base0[((size_t)(b * NNODE + i)) * 64 + s * 16 + m]
                    + (sb + r_lds[i]) * s2 + r2;
            outp[((size_t)(b * NNODE + i)) * 64 + s * 16 + m] = v;
        }
    }
}

extern "C" void kernel_launch(void* const* d_in, const int* in_sizes, int n_in,
                              void* d_out, int out_size, void* d_ws, size_t ws_size,
                              hipStream_t stream) {
    const float* A      = (const float*)d_in[0];
    const float* X      = (const float*)d_in[1];
    const float* coeffs = (const float*)d_in[2];
    const float* wA1    = (const float*)d_in[3];
    const float* wA2    = (const float*)d_in[4];
    const float* w11    = (const float*)d_in[5];
    const float* w12    = (const float*)d_in[6];
    const float* w13    = (const float*)d_in[7];
    const float* w14    = (const float*)d_in[8];
    const float* w15    = (const float*)d_in[9];
    const float* w16    = (const float*)d_in[10];
    const float* w21    = (const float*)d_in[11];
    const float* w22    = (const float*)d_in[12];
    const float* w23    = (const float*)d_in[13];
    const float* w24    = (const float*)d_in[14];
    const float* w25    = (const float*)d_in[15];
    const float* w26    = (const float*)d_in[16];

    float* ws  = (float*)d_ws;
    float* At  = (float*)d_out;
    float* out = (float*)d_out + (size_t)NGRAPH * NNODE * NNODE;

    float* rowsum = ws + OFF_ROWSUM;
    float* diagv  = ws + OFF_DIAG;
    float* p1     = ws + OFF_P1;
    float* rws    = ws + OFF_R;
    float* cspart = ws + OFF_CS;
    float* sArr   = ws + OFF_S;
    float* S2part = ws + OFF_S2P;
    float* R2part = ws + OFF_R2P;
    float* base0  = ws + OFF_BASE0;
    unsigned short* x2tg = (unsigned short*)(ws + OFF_X2T);

    kA_stats<<<NGRAPH * NNODE / 4 + NGRAPH * 8, 256, 0, stream>>>(
        A, X, wA1, rowsum, diagv, p1, cspart);
    kB_nodes<<<NGRAPH * 16, 256, 0, stream>>>(
        X, coeffs, wA2, w11, w12, w13, w14, w15, w16,
        w21, w22, w23, w24, w25, w26,
        rowsum, diagv, cspart, p1,
        rws, base0, x2tg, S2part, R2part, sArr);
    kC_main<<<NGRAPH * 16, 256, 0, stream>>>(
        A, coeffs, sArr, rws, x2tg, base0, S2part, R2part, At, out);
}